// Round 5
// baseline (874.116 us; speedup 1.0000x reference)
//
#include <hip/hip_runtime.h>
#include <stdint.h>

// ---------------------------------------------------------------------------
// EnsembleDynamicsModel fused kernel for MI355X (gfx950).
//
// Strategy: all 5 layers fused in one kernel; activations stay in LDS as
// packed split-f16 (hi,lo) u32; GEMMs run on v_mfma_f32_16x16x32_f16 with
// 3-product split precision (hh + hl + lh) for ~1e-5 relative accuracy.
// Weights are pre-converted once per call (prep kernel) into MFMA B-fragment
// layout in d_ws. Weight k-chunks are reg-prefetched (T14) into a single LDS
// buffer. 8 waves/WG = 4 rowgroups x 32 rows, N split 2-way per rowgroup.
// ---------------------------------------------------------------------------

#define EN 7
#define BN 32768
#define SD 32
#define AD 8
#define HID 200
#define OUTD 66
#define SD1 33

#define ROWS_WG 128          // 4 rowgroups * 32 rows
#define ASTR 228             // activation row stride in u32 (224 data + 4 pad)
#define WCH_WORDS 7168       // max weight chunk: 14 tiles * 512 u32 (28 KB)
#define BLOCKS_PM 364        // frag-blocks per ensemble member
// layer frag-block offsets: L0:0(28) L1:28(98) L2:126(98) L3:224(98) L4:322(42)

typedef _Float16 half8 __attribute__((ext_vector_type(8)));
typedef float f32x4 __attribute__((ext_vector_type(4)));

union HU { _Float16 f; unsigned short u; };
union V4H8 { uint4 v; half8 h; uint32_t u[4]; };

__device__ inline uint32_t pack_split(float v) {
  _Float16 h = (_Float16)v;
  _Float16 l = (_Float16)(v - (float)h);
  HU a, b; a.f = h; b.f = l;
  return ((uint32_t)b.u << 16) | (uint32_t)a.u;
}

__device__ inline float softplus_f(float x) {
  return fmaxf(x, 0.f) + log1pf(__expf(-fabsf(x)));
}

// ---------------------------------------------------------------------------
// Prep: convert fp32 weights (E,K,N) into split-f16 MFMA B-fragment blocks.
// Block (e, layer, s, t): 64 lanes * (16B hi + 16B lo).
// value = W[e][k][n], n = t*16 + (lane&15), k = s*32 + (lane>>4)*8 + j.
// ---------------------------------------------------------------------------
__global__ __launch_bounds__(256) void prep_weights(
    const float* __restrict__ W1, const float* __restrict__ W2,
    const float* __restrict__ W3, const float* __restrict__ W4,
    const float* __restrict__ W5, uint32_t* __restrict__ out)
{
  int gb = blockIdx.x * 4 + (threadIdx.x >> 6);
  int lane = threadIdx.x & 63;
  if (gb >= EN * BLOCKS_PM) return;
  int e = gb / BLOCKS_PM, r = gb % BLOCKS_PM;
  int K, N, T, off; const float* W;
  if (r < 28)       { off = 0;   T = 14; K = 40;  N = 200; W = W1; }
  else if (r < 126) { off = 28;  T = 14; K = 200; N = 200; W = W2; }
  else if (r < 224) { off = 126; T = 14; K = 200; N = 200; W = W3; }
  else if (r < 322) { off = 224; T = 14; K = 200; N = 200; W = W4; }
  else              { off = 322; T = 6;  K = 200; N = 66;  W = W5; }
  int idx = r - off;
  int s = idx / T, t = idx % T;
  int n = t * 16 + (lane & 15);
  int k0 = s * 32 + ((lane >> 4) << 3);
  const float* Wb = W + (size_t)e * K * N;
  uint32_t hi[4], lo[4];
  #pragma unroll
  for (int p = 0; p < 4; ++p) {
    float v0 = 0.f, v1 = 0.f;
    int ka = k0 + 2 * p;
    if (n < N) {
      if (ka < K)     v0 = Wb[(size_t)ka * N + n];
      if (ka + 1 < K) v1 = Wb[(size_t)(ka + 1) * N + n];
    }
    _Float16 h0 = (_Float16)v0, h1 = (_Float16)v1;
    _Float16 l0 = (_Float16)(v0 - (float)h0), l1 = (_Float16)(v1 - (float)h1);
    HU x0, x1, y0, y1; x0.f = h0; x1.f = h1; y0.f = l0; y1.f = l1;
    hi[p] = ((uint32_t)x1.u << 16) | (uint32_t)x0.u;
    lo[p] = ((uint32_t)y1.u << 16) | (uint32_t)y0.u;
  }
  uint32_t* dst = out + (size_t)gb * 512 + lane * 4;
  *(uint4*)dst         = make_uint4(hi[0], hi[1], hi[2], hi[3]);
  *(uint4*)(dst + 256) = make_uint4(lo[0], lo[1], lo[2], lo[3]);
}

// ---------------------------------------------------------------------------
// One layer: acc[2][TW] over 2 row-subtiles (16 rows each) and TW n-tiles.
// Weight chunk for k-step s+1 is prefetched into registers while computing
// k-step s from LDS, then written to LDS after the read barrier (T14).
// ---------------------------------------------------------------------------
template<int TW>
__device__ inline void compute_layer(f32x4 (&acc)[2][TW],
    const uint32_t* __restrict__ wsrc, int ksteps, int chunkWords,
    int rg, int half_, int lane, int tid,
    uint32_t* s_act, uint32_t* s_wch)
{
  const f32x4 vzero = {0.f, 0.f, 0.f, 0.f};
  #pragma unroll
  for (int rs = 0; rs < 2; ++rs)
    #pragma unroll
    for (int t = 0; t < TW; ++t)
      acc[rs][t] = vzero;

  const int units = chunkWords >> 2;       // 16B units in a chunk
  uint4 pf[4];
  uint4* wdst = (uint4*)s_wch;

  // prologue: chunk 0 -> regs -> LDS
  {
    const uint4* src = (const uint4*)wsrc;
    #pragma unroll
    for (int i = 0; i < 4; ++i) { int u = tid + i * 512; if (u < units) pf[i] = src[u]; }
  }
  #pragma unroll
  for (int i = 0; i < 4; ++i) { int u = tid + i * 512; if (u < units) wdst[u] = pf[i]; }
  __syncthreads();

  for (int s = 0; s < ksteps; ++s) {
    if (s + 1 < ksteps) {                  // issue next-chunk loads early
      const uint4* src = (const uint4*)(wsrc + (size_t)(s + 1) * chunkWords);
      #pragma unroll
      for (int i = 0; i < 4; ++i) { int u = tid + i * 512; if (u < units) pf[i] = src[u]; }
    }
    // A fragments for 2 row-subtiles: 8 contiguous packed elems each
    half8 ah[2], al[2];
    #pragma unroll
    for (int rs = 0; rs < 2; ++rs) {
      int row = rg * 32 + rs * 16 + (lane & 15);
      const uint32_t* ap = s_act + row * ASTR + s * 32 + ((lane >> 4) << 3);
      uint4 w0 = *(const uint4*)ap;
      uint4 w1 = *(const uint4*)(ap + 4);
      V4H8 Ah, Al;
      Ah.u[0] = __builtin_amdgcn_perm(w0.y, w0.x, 0x05040100u);
      Ah.u[1] = __builtin_amdgcn_perm(w0.w, w0.z, 0x05040100u);
      Ah.u[2] = __builtin_amdgcn_perm(w1.y, w1.x, 0x05040100u);
      Ah.u[3] = __builtin_amdgcn_perm(w1.w, w1.z, 0x05040100u);
      Al.u[0] = __builtin_amdgcn_perm(w0.y, w0.x, 0x07060302u);
      Al.u[1] = __builtin_amdgcn_perm(w0.w, w0.z, 0x07060302u);
      Al.u[2] = __builtin_amdgcn_perm(w1.y, w1.x, 0x07060302u);
      Al.u[3] = __builtin_amdgcn_perm(w1.w, w1.z, 0x07060302u);
      ah[rs] = Ah.h; al[rs] = Al.h;
    }
    // B fragments + 3-product split MFMA
    #pragma unroll
    for (int t = 0; t < TW; ++t) {
      const uint4* bp = ((const uint4*)(s_wch + (size_t)(half_ * TW + t) * 512)) + lane;
      V4H8 Bh, Bl; Bh.v = bp[0]; Bl.v = bp[64];
      #pragma unroll
      for (int rs = 0; rs < 2; ++rs) {
        acc[rs][t] = __builtin_amdgcn_mfma_f32_16x16x32_f16(ah[rs], Bh.h, acc[rs][t], 0, 0, 0);
        acc[rs][t] = __builtin_amdgcn_mfma_f32_16x16x32_f16(ah[rs], Bl.h, acc[rs][t], 0, 0, 0);
        acc[rs][t] = __builtin_amdgcn_mfma_f32_16x16x32_f16(al[rs], Bh.h, acc[rs][t], 0, 0, 0);
      }
    }
    __syncthreads();                       // all waves done reading s_wch
    if (s + 1 < ksteps) {
      #pragma unroll
      for (int i = 0; i < 4; ++i) { int u = tid + i * 512; if (u < units) wdst[u] = pf[i]; }
      __syncthreads();                     // chunk s+1 visible
    }
  }
}

template<int TW>
__device__ inline void store_hidden(f32x4 (&acc)[2][TW], const float* __restrict__ bias,
    int N, int rg, int half_, int lane, uint32_t* s_act)
{
  #pragma unroll
  for (int t = 0; t < TW; ++t) {
    int col = (half_ * TW + t) * 16 + (lane & 15);
    float bv = (col < N) ? bias[col] : 0.f;
    #pragma unroll
    for (int rs = 0; rs < 2; ++rs) {
      int rowb = rg * 32 + rs * 16 + ((lane >> 4) << 2);
      #pragma unroll
      for (int r = 0; r < 4; ++r) {
        float v = acc[rs][t][r] + bv;
        float sw = v / (1.f + __expf(-v));           // swish
        s_act[(rowb + r) * ASTR + col] = pack_split(sw);
      }
    }
  }
}

__global__ __launch_bounds__(512, 2) void fused_mlp(
    const float* __restrict__ state, const float* __restrict__ action,
    const float* __restrict__ noise,
    const float* __restrict__ b1, const float* __restrict__ b2,
    const float* __restrict__ b3, const float* __restrict__ b4,
    const float* __restrict__ b5,
    const float* __restrict__ maxlv, const float* __restrict__ minlv,
    const uint32_t* __restrict__ wfrag, float* __restrict__ out)
{
  __shared__ uint32_t s_act[ROWS_WG * ASTR];   // 116736 B
  __shared__ uint32_t s_wch[WCH_WORDS];        //  28672 B
  int tid = threadIdx.x, lane = tid & 63, wave = tid >> 6;
  int rg = wave >> 1, half_ = wave & 1;
  const int nwg_pm = BN / ROWS_WG;             // 256
  int bid = blockIdx.x;
  int swz = (bid & 7) * ((EN * nwg_pm) >> 3) + (bid >> 3);  // XCD swizzle (1792%8==0)
  int e = swz / nwg_pm;
  int rowbase = (swz % nwg_pm) * ROWS_WG;

  // phase 0: load x = concat(state, action), zero-pad cols 40..63
  for (int i = tid; i < ROWS_WG * 64; i += 512) {
    int r = i >> 6, c = i & 63;
    int grow = rowbase + r;
    float v = 0.f;
    if (c < SD) v = state[(size_t)grow * SD + c];
    else if (c < SD + AD) v = action[(size_t)grow * AD + (c - SD)];
    s_act[r * ASTR + c] = pack_split(v);
  }
  __syncthreads();

  const uint32_t* wmem = wfrag + (size_t)e * (BLOCKS_PM * 512);
  f32x4 acc[2][7];

  compute_layer<7>(acc, wmem,             2, 14 * 512, rg, half_, lane, tid, s_act, s_wch);
  store_hidden<7>(acc, b1 + e * HID, HID, rg, half_, lane, s_act);
  __syncthreads();
  compute_layer<7>(acc, wmem + 28 * 512,  7, 14 * 512, rg, half_, lane, tid, s_act, s_wch);
  store_hidden<7>(acc, b2 + e * HID, HID, rg, half_, lane, s_act);
  __syncthreads();
  compute_layer<7>(acc, wmem + 126 * 512, 7, 14 * 512, rg, half_, lane, tid, s_act, s_wch);
  store_hidden<7>(acc, b3 + e * HID, HID, rg, half_, lane, s_act);
  __syncthreads();
  compute_layer<7>(acc, wmem + 224 * 512, 7, 14 * 512, rg, half_, lane, tid, s_act, s_wch);
  store_hidden<7>(acc, b4 + e * HID, HID, rg, half_, lane, s_act);
  __syncthreads();

  f32x4 acc5[2][3];
  compute_layer<3>(acc5, wmem + 322 * 512, 7, 6 * 512, rg, half_, lane, tid, s_act, s_wch);

  // layer-5 epilogue: mean / std into LDS overlay (s_act region is dead now)
  float* meanb = (float*)s_act;                // [128][34]
  float* stdb  = meanb + ROWS_WG * 34;         // [128][34]
  {
    const float* bias5 = b5 + e * OUTD;
    #pragma unroll
    for (int t = 0; t < 3; ++t) {
      int col = (half_ * 3 + t) * 16 + (lane & 15);
      #pragma unroll
      for (int rs = 0; rs < 2; ++rs) {
        int rowb = rg * 32 + rs * 16 + ((lane >> 4) << 2);
        #pragma unroll
        for (int r = 0; r < 4; ++r) {
          float v = acc5[rs][t][r];
          if (col < SD1) {
            meanb[(rowb + r) * 34 + col] = v + bias5[col];
          } else if (col < OUTD) {
            int c2 = col - SD1;
            float lv = v + bias5[col];
            float mx = maxlv[c2], mn = minlv[c2];
            lv = mx - softplus_f(mx - lv);
            lv = mn + softplus_f(lv - mn);
            stdb[(rowb + r) * 34 + c2] = __expf(0.5f * lv);
          }
        }
      }
    }
  }
  __syncthreads();

  // outputs: next_states (E,B,32) then rewards (E,B)
  const float* nz = noise + (size_t)e * BN * SD1;
  for (int i = tid; i < ROWS_WG * SD; i += 512) {
    int r = i >> 5, c = i & 31;
    int grow = rowbase + r;
    float m = meanb[r * 34 + c], sdv = stdb[r * 34 + c];
    float n0 = nz[(size_t)grow * SD1 + c];
    out[((size_t)e * BN + grow) * SD + c] = state[(size_t)grow * SD + c] + m + sdv * n0;
  }
  if (tid < ROWS_WG) {
    int grow = rowbase + tid;
    float m = meanb[tid * 34 + SD], sdv = stdb[tid * 34 + SD];
    out[(size_t)EN * BN * SD + (size_t)e * BN + grow] =
        m + sdv * nz[(size_t)grow * SD1 + SD];
  }
}

extern "C" void kernel_launch(void* const* d_in, const int* in_sizes, int n_in,
                              void* d_out, int out_size, void* d_ws, size_t ws_size,
                              hipStream_t stream)
{
  (void)in_sizes; (void)n_in; (void)out_size; (void)ws_size;
  const float* state  = (const float*)d_in[0];
  const float* action = (const float*)d_in[1];
  const float* noise  = (const float*)d_in[2];
  const float* W1 = (const float*)d_in[3];  const float* b1 = (const float*)d_in[4];
  const float* W2 = (const float*)d_in[5];  const float* b2 = (const float*)d_in[6];
  const float* W3 = (const float*)d_in[7];  const float* b3 = (const float*)d_in[8];
  const float* W4 = (const float*)d_in[9];  const float* b4 = (const float*)d_in[10];
  const float* W5 = (const float*)d_in[11]; const float* b5 = (const float*)d_in[12];
  const float* mx = (const float*)d_in[13]; const float* mn = (const float*)d_in[14];
  uint32_t* wfrag = (uint32_t*)d_ws;        // needs 7*364*512*4 = 5.2 MB

  int nfb = EN * BLOCKS_PM;                 // 2548 frag-blocks
  prep_weights<<<(nfb + 3) / 4, 256, 0, stream>>>(W1, W2, W3, W4, W5, wfrag);
  fused_mlp<<<EN * (BN / ROWS_WG), 512, 0, stream>>>(
      state, action, noise, b1, b2, b3, b4, b5, mx, mn, wfrag, (float*)d_out);
}

// Round 7
// 571.963 us; speedup vs baseline: 1.5283x; 1.5283x over previous
//
#include <hip/hip_runtime.h>
#include <stdint.h>

// ---------------------------------------------------------------------------
// EnsembleDynamicsModel fused kernel for MI355X (gfx950) — round 2 structure.
// Changes vs prior (stall-bound at 1 WG/CU, 2 waves/SIMD, 9.5K cyc/k-step):
//  * 1024-thread WG (16 waves = 4 rowgroups x 4 colgroups) -> 4 waves/SIMD
//  * single barrier per k-step: weight chunks double-buffered in LDS, staged
//    with global_load_lds(16B) one step ahead (no reg round-trip, no vmcnt(0)
//    +ds_write serial segment)
//  * LDS 157.7 KB: s_act 128x204 packed split-f16 (no k-padding; last k-step
//    is shifted to k 168..199 with weight rows 168..191 zeroed in prep) +
//    2 x 13-tile weight chunks.
// ---------------------------------------------------------------------------

#define EN 7
#define BN 32768
#define SD 32
#define AD 8
#define HID 200
#define OUTD 66
#define SD1 33

#define ROWS_WG 128
#define ASTR 204             // u32/row; 204%32=12 -> 2-way banks (free)
#define NT 13                // n-tiles, hidden layers (208 >= 200)
#define NT5 5                // n-tiles, layer 5 (80 >= 66)
#define CHW (NT * 512)       // 6656 u32 = 26624 B per chunk
#define BLOCKS_PM 334        // 2*13 + 3*7*13 + 7*5
// layer block offsets: L1:0(26) L2:26(91) L3:117(91) L4:208(91) L5:299(35)

typedef _Float16 half8 __attribute__((ext_vector_type(8)));
typedef float f32x4 __attribute__((ext_vector_type(4)));

union HU { _Float16 f; unsigned short u; };
union V4H8 { uint4 v; half8 h; uint32_t u[4]; };

__device__ inline uint32_t pack_split(float v) {
  _Float16 h = (_Float16)v;
  _Float16 l = (_Float16)(v - (float)h);
  HU a, b; a.f = h; b.f = l;
  return ((uint32_t)b.u << 16) | (uint32_t)a.u;
}

__device__ inline float softplus_f(float x) {
  return fmaxf(x, 0.f) + log1pf(__expf(-fabsf(x)));
}

// ---------------------------------------------------------------------------
// Prep: fp32 weights (E,K,N) -> split-f16 MFMA B-fragment blocks.
// Block (e,layer,s,t): 64 lanes * (16B hi + 16B lo); value = W[e][k][n],
// n = t*16 + (lane&15), k = kbase + (lane>>4)*8 + j.
// Shifted last k-step (K=200 layers): kbase=168, rows k<192 zeroed.
// ---------------------------------------------------------------------------
__global__ __launch_bounds__(256) void prep_weights(
    const float* __restrict__ W1, const float* __restrict__ W2,
    const float* __restrict__ W3, const float* __restrict__ W4,
    const float* __restrict__ W5, uint32_t* __restrict__ out)
{
  int gb = blockIdx.x * 4 + (threadIdx.x >> 6);
  int lane = threadIdx.x & 63;
  if (gb >= EN * BLOCKS_PM) return;
  int e = gb / BLOCKS_PM, r = gb % BLOCKS_PM;
  int K, N, T, off; const float* W; bool shift;
  if (r < 26)       { off = 0;   T = NT;  K = 40;  N = 200; W = W1; shift = false; }
  else if (r < 117) { off = 26;  T = NT;  K = 200; N = 200; W = W2; shift = true;  }
  else if (r < 208) { off = 117; T = NT;  K = 200; N = 200; W = W3; shift = true;  }
  else if (r < 299) { off = 208; T = NT;  K = 200; N = 200; W = W4; shift = true;  }
  else              { off = 299; T = NT5; K = 200; N = 66;  W = W5; shift = true;  }
  int idx = r - off;
  int s = idx / T, t = idx % T;
  bool sh = shift && (s == 6);
  int kbase = sh ? 168 : s * 32;
  int kmin  = sh ? 192 : 0;
  int n = t * 16 + (lane & 15);
  int k0 = kbase + ((lane >> 4) << 3);
  const float* Wb = W + (size_t)e * K * N;
  uint32_t hi[4], lo[4];
  #pragma unroll
  for (int p = 0; p < 4; ++p) {
    float v0 = 0.f, v1 = 0.f;
    int ka = k0 + 2 * p;
    if (n < N) {
      if (ka >= kmin && ka < K)         v0 = Wb[(size_t)ka * N + n];
      if (ka + 1 >= kmin && ka + 1 < K) v1 = Wb[(size_t)(ka + 1) * N + n];
    }
    _Float16 h0 = (_Float16)v0, h1 = (_Float16)v1;
    _Float16 l0 = (_Float16)(v0 - (float)h0), l1 = (_Float16)(v1 - (float)h1);
    HU x0, x1, y0, y1; x0.f = h0; x1.f = h1; y0.f = l0; y1.f = l1;
    hi[p] = ((uint32_t)x1.u << 16) | (uint32_t)x0.u;
    lo[p] = ((uint32_t)y1.u << 16) | (uint32_t)y0.u;
  }
  uint32_t* dst = out + (size_t)gb * 512 + lane * 4;
  *(uint4*)dst         = make_uint4(hi[0], hi[1], hi[2], hi[3]);
  *(uint4*)(dst + 256) = make_uint4(lo[0], lo[1], lo[2], lo[3]);
}

// ---------------------------------------------------------------------------
// global_load_lds 16B: per-lane global src, wave-uniform LDS base (+lane*16 HW)
// ---------------------------------------------------------------------------
__device__ inline void gload16(const uint32_t* g, uint32_t* l) {
  __builtin_amdgcn_global_load_lds(
      (const __attribute__((address_space(1))) uint32_t*)g,
      (__attribute__((address_space(3))) uint32_t*)l, 16, 0, 0);
}

// stage one weight chunk (UNITS x 16B) cooperatively, no waits
template<int UNITS>
__device__ inline void stage_chunk(const uint32_t* __restrict__ src,
                                   uint32_t* dst, int tid) {
  int wv = tid >> 6, ln = tid & 63;
  #pragma unroll
  for (int i = 0; i < (UNITS + 1023) / 1024; ++i) {
    int u0 = i * 1024 + wv * 64;          // wave-uniform
    if (u0 < UNITS) gload16(src + (size_t)(u0 + ln) * 4, dst + (size_t)u0 * 4);
  }
}

// ---------------------------------------------------------------------------
// One layer: acc[2][TW]; k-step s reads buf[s&1], stages chunk s+1 -> buf[~s&1]
// ---------------------------------------------------------------------------
template<int TW, int TILES, bool SHIFT>
__device__ void compute_layer(f32x4 (&acc)[2][4],
    const uint32_t* __restrict__ wsrc, int ksteps, int tb,
    int rg, int lane, int tid,
    uint32_t* s_act, uint32_t* buf0, uint32_t* buf1)
{
  const f32x4 vzero = {0.f, 0.f, 0.f, 0.f};
  #pragma unroll
  for (int rs = 0; rs < 2; ++rs)
    #pragma unroll
    for (int t = 0; t < TW; ++t)
      acc[rs][t] = vzero;

  for (int s = 0; s < ksteps; ++s) {
    uint32_t* cur = (s & 1) ? buf1 : buf0;
    uint32_t* nxt = (s & 1) ? buf0 : buf1;
    if (s + 1 < ksteps)
      stage_chunk<TILES * 128>(wsrc + (size_t)(s + 1) * TILES * 512, nxt, tid);

    int kcol = (SHIFT && s == ksteps - 1) ? 168 : s * 32;
    half8 ah[2], al[2];
    #pragma unroll
    for (int rs = 0; rs < 2; ++rs) {
      int row = rg * 32 + rs * 16 + (lane & 15);
      const uint32_t* ap = s_act + row * ASTR + kcol + ((lane >> 4) << 3);
      uint4 w0 = *(const uint4*)ap;
      uint4 w1 = *(const uint4*)(ap + 4);
      V4H8 Ah, Al;
      Ah.u[0] = __builtin_amdgcn_perm(w0.y, w0.x, 0x05040100u);
      Ah.u[1] = __builtin_amdgcn_perm(w0.w, w0.z, 0x05040100u);
      Ah.u[2] = __builtin_amdgcn_perm(w1.y, w1.x, 0x05040100u);
      Ah.u[3] = __builtin_amdgcn_perm(w1.w, w1.z, 0x05040100u);
      Al.u[0] = __builtin_amdgcn_perm(w0.y, w0.x, 0x07060302u);
      Al.u[1] = __builtin_amdgcn_perm(w0.w, w0.z, 0x07060302u);
      Al.u[2] = __builtin_amdgcn_perm(w1.y, w1.x, 0x07060302u);
      Al.u[3] = __builtin_amdgcn_perm(w1.w, w1.z, 0x07060302u);
      ah[rs] = Ah.h; al[rs] = Al.h;
    }
    #pragma unroll
    for (int t = 0; t < TW; ++t) {
      const uint4* bp = ((const uint4*)(cur + (size_t)(tb + t) * 512)) + lane;
      V4H8 Bh, Bl; Bh.v = bp[0]; Bl.v = bp[64];
      #pragma unroll
      for (int rs = 0; rs < 2; ++rs) {
        acc[rs][t] = __builtin_amdgcn_mfma_f32_16x16x32_f16(ah[rs], Bh.h, acc[rs][t], 0, 0, 0);
        acc[rs][t] = __builtin_amdgcn_mfma_f32_16x16x32_f16(ah[rs], Bl.h, acc[rs][t], 0, 0, 0);
        acc[rs][t] = __builtin_amdgcn_mfma_f32_16x16x32_f16(al[rs], Bh.h, acc[rs][t], 0, 0, 0);
      }
    }
    __syncthreads();   // single barrier per k-step
  }
}

template<int TW>
__device__ inline void store_hidden(f32x4 (&acc)[2][4], const float* __restrict__ bias,
    int tb, int rg, int lane, uint32_t* s_act)
{
  #pragma unroll
  for (int t = 0; t < TW; ++t) {
    int col = (tb + t) * 16 + (lane & 15);
    if (col < HID) {
      float bv = bias[col];
      #pragma unroll
      for (int rs = 0; rs < 2; ++rs) {
        int rowb = rg * 32 + rs * 16 + ((lane >> 4) << 2);
        #pragma unroll
        for (int r = 0; r < 4; ++r) {
          float v = acc[rs][t][r] + bv;
          float sw = v / (1.f + __expf(-v));        // swish
          s_act[(rowb + r) * ASTR + col] = pack_split(sw);
        }
      }
    }
  }
}

template<int TW, int TW5>
__device__ void run_all(int tb, int tb5, int rg, int lane, int tid,
    const uint32_t* __restrict__ wm,
    const float* __restrict__ b1, const float* __restrict__ b2,
    const float* __restrict__ b3, const float* __restrict__ b4,
    const float* __restrict__ b5,
    const float* __restrict__ maxlv, const float* __restrict__ minlv,
    uint32_t* s_act, uint32_t* buf0, uint32_t* buf1)
{
  f32x4 acc[2][4];

  compute_layer<TW, NT, false>(acc, wm, 2, tb, rg, lane, tid, s_act, buf0, buf1);
  stage_chunk<NT * 128>(wm + (size_t)26 * 512, buf0, tid);     // L2 chunk0
  store_hidden<TW>(acc, b1, tb, rg, lane, s_act);
  __syncthreads();

  compute_layer<TW, NT, true>(acc, wm + (size_t)26 * 512, 7, tb, rg, lane, tid, s_act, buf0, buf1);
  stage_chunk<NT * 128>(wm + (size_t)117 * 512, buf0, tid);    // L3 chunk0
  store_hidden<TW>(acc, b2, tb, rg, lane, s_act);
  __syncthreads();

  compute_layer<TW, NT, true>(acc, wm + (size_t)117 * 512, 7, tb, rg, lane, tid, s_act, buf0, buf1);
  stage_chunk<NT * 128>(wm + (size_t)208 * 512, buf0, tid);    // L4 chunk0
  store_hidden<TW>(acc, b3, tb, rg, lane, s_act);
  __syncthreads();

  compute_layer<TW, NT, true>(acc, wm + (size_t)208 * 512, 7, tb, rg, lane, tid, s_act, buf0, buf1);
  stage_chunk<NT5 * 128>(wm + (size_t)299 * 512, buf0, tid);   // L5 chunk0
  store_hidden<TW>(acc, b4, tb, rg, lane, s_act);
  __syncthreads();

  compute_layer<TW5, NT5, true>(acc, wm + (size_t)299 * 512, 7, tb5, rg, lane, tid, s_act, buf0, buf1);

  // L5 epilogue: mean/std into LDS overlay (s_act dead after last barrier)
  float* meanb = (float*)s_act;                 // [128][34]
  float* stdb  = meanb + ROWS_WG * 34;          // [128][34]
  #pragma unroll
  for (int t = 0; t < TW5; ++t) {
    int col = (tb5 + t) * 16 + (lane & 15);
    if (col < OUTD) {
      float bv = b5[col];
      #pragma unroll
      for (int rs = 0; rs < 2; ++rs) {
        int rowb = rg * 32 + rs * 16 + ((lane >> 4) << 2);
        #pragma unroll
        for (int r = 0; r < 4; ++r) {
          float v = acc[rs][t][r] + bv;
          if (col < SD1) {
            meanb[(rowb + r) * 34 + col] = v;
          } else {
            int c2 = col - SD1;
            float lv = v;
            float mx = maxlv[c2], mn = minlv[c2];
            lv = mx - softplus_f(mx - lv);
            lv = mn + softplus_f(lv - mn);
            stdb[(rowb + r) * 34 + c2] = __expf(0.5f * lv);
          }
        }
      }
    }
  }
}

__global__ __launch_bounds__(1024, 4) void fused_mlp(
    const float* __restrict__ state, const float* __restrict__ action,
    const float* __restrict__ noise,
    const float* __restrict__ b1, const float* __restrict__ b2,
    const float* __restrict__ b3, const float* __restrict__ b4,
    const float* __restrict__ b5,
    const float* __restrict__ maxlv, const float* __restrict__ minlv,
    const uint32_t* __restrict__ wfrag, float* __restrict__ out)
{
  __shared__ uint32_t s_act[ROWS_WG * ASTR];     // 104448 B
  __shared__ uint32_t s_wch[2][CHW];             //  53248 B (157696 total)
  const int tid = threadIdx.x, lane = tid & 63, wave = tid >> 6;
  const int rg = wave >> 2, cg = wave & 3;
  const int nwg_pm = BN / ROWS_WG;               // 256
  int bid = blockIdx.x;
  int swz = (bid & 7) * ((EN * nwg_pm) >> 3) + (bid >> 3);   // 1792 % 8 == 0
  int e = swz / nwg_pm;
  int rowbase = (swz % nwg_pm) * ROWS_WG;

  const uint32_t* wm = wfrag + (size_t)e * (BLOCKS_PM * 512);
  uint32_t* buf0 = &s_wch[0][0];
  uint32_t* buf1 = &s_wch[1][0];

  stage_chunk<NT * 128>(wm, buf0, tid);          // L1 chunk0 (overlaps phase 0)

  // phase 0: x = concat(state, action); cols 40..63 zero
  for (int i = tid; i < ROWS_WG * 64; i += 1024) {
    int r = i >> 6, c = i & 63;
    int grow = rowbase + r;
    float v = 0.f;
    if (c < SD) v = state[(size_t)grow * SD + c];
    else if (c < SD + AD) v = action[(size_t)grow * AD + (c - SD)];
    s_act[r * ASTR + c] = pack_split(v);
  }
  __syncthreads();

  if (cg == 0)
    run_all<4, 2>(0, 0, rg, lane, tid, wm, b1 + e * HID, b2 + e * HID,
                  b3 + e * HID, b4 + e * HID, b5 + e * OUTD, maxlv, minlv,
                  s_act, buf0, buf1);
  else
    run_all<3, 1>(4 + 3 * (cg - 1), 2 + (cg - 1), rg, lane, tid, wm,
                  b1 + e * HID, b2 + e * HID, b3 + e * HID, b4 + e * HID,
                  b5 + e * OUTD, maxlv, minlv, s_act, buf0, buf1);
  __syncthreads();

  // outputs: next_states (E,B,32) then rewards (E,B)
  float* meanb = (float*)s_act;
  float* stdb  = meanb + ROWS_WG * 34;
  const float* nz = noise + (size_t)e * BN * SD1;
  for (int i = tid; i < ROWS_WG * SD; i += 1024) {
    int r = i >> 5, c = i & 31;
    int grow = rowbase + r;
    float m = meanb[r * 34 + c], sdv = stdb[r * 34 + c];
    float n0 = nz[(size_t)grow * SD1 + c];
    out[((size_t)e * BN + grow) * SD + c] = state[(size_t)grow * SD + c] + m + sdv * n0;
  }
  if (tid < ROWS_WG) {
    int grow = rowbase + tid;
    float m = meanb[tid * 34 + SD], sdv = stdb[tid * 34 + SD];
    out[(size_t)EN * BN * SD + (size_t)e * BN + grow] =
        m + sdv * nz[(size_t)grow * SD1 + SD];
  }
}

extern "C" void kernel_launch(void* const* d_in, const int* in_sizes, int n_in,
                              void* d_out, int out_size, void* d_ws, size_t ws_size,
                              hipStream_t stream)
{
  (void)in_sizes; (void)n_in; (void)out_size; (void)ws_size;
  const float* state  = (const float*)d_in[0];
  const float* action = (const float*)d_in[1];
  const float* noise  = (const float*)d_in[2];
  const float* W1 = (const float*)d_in[3];  const float* b1 = (const float*)d_in[4];
  const float* W2 = (const float*)d_in[5];  const float* b2 = (const float*)d_in[6];
  const float* W3 = (const float*)d_in[7];  const float* b3 = (const float*)d_in[8];
  const float* W4 = (const float*)d_in[9];  const float* b4 = (const float*)d_in[10];
  const float* W5 = (const float*)d_in[11]; const float* b5 = (const float*)d_in[12];
  const float* mx = (const float*)d_in[13]; const float* mn = (const float*)d_in[14];
  uint32_t* wfrag = (uint32_t*)d_ws;        // 7*334*2048 B = 4.79 MB

  int nfb = EN * BLOCKS_PM;                 // 2338 frag-blocks
  prep_weights<<<(nfb + 3) / 4, 256, 0, stream>>>(W1, W2, W3, W4, W5, wfrag);
  fused_mlp<<<EN * (BN / ROWS_WG), 1024, 0, stream>>>(
      state, action, noise, b1, b2, b3, b4, b5, mx, mn, wfrag, (float*)d_out);
}

// Round 8
// 433.794 us; speedup vs baseline: 2.0151x; 1.3185x over previous
//
#include <hip/hip_runtime.h>
#include <stdint.h>

// ---------------------------------------------------------------------------
// EnsembleDynamicsModel fused kernel for MI355X (gfx950) — round 3 structure.
// vs round 2 (537 us, no pipe >50%, 6140 cyc/k-step, VALU-heavy):
//  * activations stored PLAIN f16 (split-f16 dropped on A): MFMA 3->2
//    products, A-frag = 1 ds_read_b128 per rs (no v_perm extraction),
//    s_act halved -> LDS/WG = 80 KB exactly -> 2 WGs/CU (split barrier
//    domains overlap each other's stalls). B stays split-f16 (hi+lo).
//  * 512-thread WG = 8 waves = 2 rowgroups x 4 colgroups, 64 rows/WG.
// ---------------------------------------------------------------------------

#define EN 7
#define BN 32768
#define SD 32
#define AD 8
#define HID 200
#define OUTD 66
#define SD1 33

#define ROWS_WG 64
#define AST 224              // f16 per activation row (64*224*2 = 28672 B)
#define NT 13                // n-tiles, hidden layers
#define NT5 5                // n-tiles, layer 5
#define CHW (NT * 512)       // 6656 u32 = 26624 B per weight chunk
#define BLOCKS_PM 334        // 2*13 + 3*7*13 + 7*5
// layer block offsets: L1:0(26) L2:26(91) L3:117(91) L4:208(91) L5:299(35)

typedef _Float16 half8 __attribute__((ext_vector_type(8)));
typedef float f32x4 __attribute__((ext_vector_type(4)));

union HU { _Float16 f; unsigned short u; };
union V4H8 { uint4 v; half8 h; };

__device__ inline float softplus_f(float x) {
  return fmaxf(x, 0.f) + log1pf(__expf(-fabsf(x)));
}

// ---------------------------------------------------------------------------
// Prep: fp32 weights (E,K,N) -> split-f16 MFMA B-fragment blocks (UNCHANGED
// from round 2 — verified). Block (e,layer,s,t): 64 lanes * (16B hi+16B lo);
// value = W[e][k][n], n = t*16+(lane&15), k = kbase+(lane>>4)*8+j.
// Shifted last k-step (K=200 layers): kbase=168, rows k<192 zeroed.
// ---------------------------------------------------------------------------
__global__ __launch_bounds__(256) void prep_weights(
    const float* __restrict__ W1, const float* __restrict__ W2,
    const float* __restrict__ W3, const float* __restrict__ W4,
    const float* __restrict__ W5, uint32_t* __restrict__ out)
{
  int gb = blockIdx.x * 4 + (threadIdx.x >> 6);
  int lane = threadIdx.x & 63;
  if (gb >= EN * BLOCKS_PM) return;
  int e = gb / BLOCKS_PM, r = gb % BLOCKS_PM;
  int K, N, T, off; const float* W; bool shift;
  if (r < 26)       { off = 0;   T = NT;  K = 40;  N = 200; W = W1; shift = false; }
  else if (r < 117) { off = 26;  T = NT;  K = 200; N = 200; W = W2; shift = true;  }
  else if (r < 208) { off = 117; T = NT;  K = 200; N = 200; W = W3; shift = true;  }
  else if (r < 299) { off = 208; T = NT;  K = 200; N = 200; W = W4; shift = true;  }
  else              { off = 299; T = NT5; K = 200; N = 66;  W = W5; shift = true;  }
  int idx = r - off;
  int s = idx / T, t = idx % T;
  bool sh = shift && (s == 6);
  int kbase = sh ? 168 : s * 32;
  int kmin  = sh ? 192 : 0;
  int n = t * 16 + (lane & 15);
  int k0 = kbase + ((lane >> 4) << 3);
  const float* Wb = W + (size_t)e * K * N;
  uint32_t hi[4], lo[4];
  #pragma unroll
  for (int p = 0; p < 4; ++p) {
    float v0 = 0.f, v1 = 0.f;
    int ka = k0 + 2 * p;
    if (n < N) {
      if (ka >= kmin && ka < K)         v0 = Wb[(size_t)ka * N + n];
      if (ka + 1 >= kmin && ka + 1 < K) v1 = Wb[(size_t)(ka + 1) * N + n];
    }
    _Float16 h0 = (_Float16)v0, h1 = (_Float16)v1;
    _Float16 l0 = (_Float16)(v0 - (float)h0), l1 = (_Float16)(v1 - (float)h1);
    HU x0, x1, y0, y1; x0.f = h0; x1.f = h1; y0.f = l0; y1.f = l1;
    hi[p] = ((uint32_t)x1.u << 16) | (uint32_t)x0.u;
    lo[p] = ((uint32_t)y1.u << 16) | (uint32_t)y0.u;
  }
  uint32_t* dst = out + (size_t)gb * 512 + lane * 4;
  *(uint4*)dst         = make_uint4(hi[0], hi[1], hi[2], hi[3]);
  *(uint4*)(dst + 256) = make_uint4(lo[0], lo[1], lo[2], lo[3]);
}

// ---------------------------------------------------------------------------
// global_load_lds 16B: per-lane global src, wave-uniform LDS base (+lane*16)
// ---------------------------------------------------------------------------
__device__ inline void gload16(const uint32_t* g, uint32_t* l) {
  __builtin_amdgcn_global_load_lds(
      (const __attribute__((address_space(1))) uint32_t*)g,
      (__attribute__((address_space(3))) uint32_t*)l, 16, 0, 0);
}

// stage one weight chunk (UNITS x 16B) cooperatively (512-thread WG)
template<int UNITS>
__device__ inline void stage_chunk(const uint32_t* __restrict__ src,
                                   uint32_t* dst, int tid) {
  int wv = tid >> 6, ln = tid & 63;
  #pragma unroll
  for (int i = 0; i < (UNITS + 511) / 512; ++i) {
    int u0 = i * 512 + wv * 64;           // wave-uniform LDS base
    if (u0 < UNITS) gload16(src + (size_t)(u0 + ln) * 4, dst + (size_t)u0 * 4);
  }
}

// ---------------------------------------------------------------------------
// One layer: acc[2][TW]; k-step s reads buf[s&1], stages chunk s+1 -> other.
// A: plain f16, one b128 per row-subtile. B: split hi/lo, 2 MFMA products.
// ---------------------------------------------------------------------------
template<int TW, int TILES, bool SHIFT>
__device__ void compute_layer(f32x4 (&acc)[2][4],
    const uint32_t* __restrict__ wsrc, int ksteps, int tb,
    int rg, int lane, int tid,
    const _Float16* s_act, uint32_t* buf0, uint32_t* buf1)
{
  const f32x4 vzero = {0.f, 0.f, 0.f, 0.f};
  #pragma unroll
  for (int rs = 0; rs < 2; ++rs)
    #pragma unroll
    for (int t = 0; t < TW; ++t)
      acc[rs][t] = vzero;

  for (int s = 0; s < ksteps; ++s) {
    uint32_t* cur = (s & 1) ? buf1 : buf0;
    uint32_t* nxt = (s & 1) ? buf0 : buf1;
    if (s + 1 < ksteps)
      stage_chunk<TILES * 128>(wsrc + (size_t)(s + 1) * TILES * 512, nxt, tid);

    int kcol = (SHIFT && s == ksteps - 1) ? 168 : s * 32;
    half8 a[2];
    #pragma unroll
    for (int rs = 0; rs < 2; ++rs) {
      int row = rg * 32 + rs * 16 + (lane & 15);
      a[rs] = *(const half8*)(s_act + row * AST + kcol + ((lane >> 4) << 3));
    }
    #pragma unroll
    for (int t = 0; t < TW; ++t) {
      const uint4* bp = ((const uint4*)(cur + (size_t)(tb + t) * 512)) + lane;
      V4H8 Bh, Bl; Bh.v = bp[0]; Bl.v = bp[64];
      #pragma unroll
      for (int rs = 0; rs < 2; ++rs) {
        acc[rs][t] = __builtin_amdgcn_mfma_f32_16x16x32_f16(a[rs], Bh.h, acc[rs][t], 0, 0, 0);
        acc[rs][t] = __builtin_amdgcn_mfma_f32_16x16x32_f16(a[rs], Bl.h, acc[rs][t], 0, 0, 0);
      }
    }
    __syncthreads();                      // single barrier per k-step
  }
}

template<int TW>
__device__ inline void store_hidden(f32x4 (&acc)[2][4], const float* __restrict__ bias,
    int tb, int rg, int lane, _Float16* s_act)
{
  #pragma unroll
  for (int t = 0; t < TW; ++t) {
    int col = (tb + t) * 16 + (lane & 15);
    if (col < HID) {
      float bv = bias[col];
      #pragma unroll
      for (int rs = 0; rs < 2; ++rs) {
        int rowb = rg * 32 + rs * 16 + ((lane >> 4) << 2);
        #pragma unroll
        for (int r = 0; r < 4; ++r) {
          float v = acc[rs][t][r] + bv;
          float sw = v / (1.f + __expf(-v));       // swish
          s_act[(rowb + r) * AST + col] = (_Float16)sw;
        }
      }
    }
  }
}

template<int TW, int TW5>
__device__ void run_all(int tb, int tb5, int rg, int lane, int tid,
    const uint32_t* __restrict__ wm,
    const float* __restrict__ b1, const float* __restrict__ b2,
    const float* __restrict__ b3, const float* __restrict__ b4,
    const float* __restrict__ b5,
    const float* __restrict__ maxlv, const float* __restrict__ minlv,
    _Float16* s_act, uint32_t* buf0, uint32_t* buf1)
{
  f32x4 acc[2][4];

  compute_layer<TW, NT, false>(acc, wm, 2, tb, rg, lane, tid, s_act, buf0, buf1);
  stage_chunk<NT * 128>(wm + (size_t)26 * 512, buf0, tid);     // L2 chunk0
  store_hidden<TW>(acc, b1, tb, rg, lane, s_act);
  __syncthreads();

  compute_layer<TW, NT, true>(acc, wm + (size_t)26 * 512, 7, tb, rg, lane, tid, s_act, buf0, buf1);
  stage_chunk<NT * 128>(wm + (size_t)117 * 512, buf0, tid);    // L3 chunk0
  store_hidden<TW>(acc, b2, tb, rg, lane, s_act);
  __syncthreads();

  compute_layer<TW, NT, true>(acc, wm + (size_t)117 * 512, 7, tb, rg, lane, tid, s_act, buf0, buf1);
  stage_chunk<NT * 128>(wm + (size_t)208 * 512, buf0, tid);    // L4 chunk0
  store_hidden<TW>(acc, b3, tb, rg, lane, s_act);
  __syncthreads();

  compute_layer<TW, NT, true>(acc, wm + (size_t)208 * 512, 7, tb, rg, lane, tid, s_act, buf0, buf1);
  stage_chunk<NT5 * 128>(wm + (size_t)299 * 512, buf0, tid);   // L5 chunk0
  store_hidden<TW>(acc, b4, tb, rg, lane, s_act);
  __syncthreads();

  compute_layer<TW5, NT5, true>(acc, wm + (size_t)299 * 512, 7, tb5, rg, lane, tid, s_act, buf0, buf1);

  // L5 epilogue: mean/std into LDS overlay (s_act dead after last barrier)
  float* meanb = (float*)s_act;                 // [64][34]
  float* stdb  = meanb + ROWS_WG * 34;          // [64][34]
  #pragma unroll
  for (int t = 0; t < TW5; ++t) {
    int col = (tb5 + t) * 16 + (lane & 15);
    if (col < OUTD) {
      float bv = b5[col];
      #pragma unroll
      for (int rs = 0; rs < 2; ++rs) {
        int rowb = rg * 32 + rs * 16 + ((lane >> 4) << 2);
        #pragma unroll
        for (int r = 0; r < 4; ++r) {
          float v = acc[rs][t][r] + bv;
          if (col < SD1) {
            meanb[(rowb + r) * 34 + col] = v;
          } else {
            int c2 = col - SD1;
            float lv = v;
            float mx = maxlv[c2], mn = minlv[c2];
            lv = mx - softplus_f(mx - lv);
            lv = mn + softplus_f(lv - mn);
            stdb[(rowb + r) * 34 + c2] = __expf(0.5f * lv);
          }
        }
      }
    }
  }
}

__global__ __launch_bounds__(512, 4) void fused_mlp(
    const float* __restrict__ state, const float* __restrict__ action,
    const float* __restrict__ noise,
    const float* __restrict__ b1, const float* __restrict__ b2,
    const float* __restrict__ b3, const float* __restrict__ b4,
    const float* __restrict__ b5,
    const float* __restrict__ maxlv, const float* __restrict__ minlv,
    const uint32_t* __restrict__ wfrag, float* __restrict__ out)
{
  __shared__ __align__(16) _Float16 s_act[ROWS_WG * AST];  // 28672 B
  __shared__ uint32_t s_wch[2][CHW];                       // 53248 B (81920 total)
  const int tid = threadIdx.x, lane = tid & 63, wave = tid >> 6;
  const int rg = wave >> 2, cg = wave & 3;
  const int nwg_pm = BN / ROWS_WG;               // 512
  int bid = blockIdx.x;
  int swz = (bid & 7) * ((EN * nwg_pm) >> 3) + (bid >> 3);   // 3584 % 8 == 0
  int e = swz / nwg_pm;
  int rowbase = (swz % nwg_pm) * ROWS_WG;

  const uint32_t* wm = wfrag + (size_t)e * (BLOCKS_PM * 512);
  uint32_t* buf0 = &s_wch[0][0];
  uint32_t* buf1 = &s_wch[1][0];

  stage_chunk<NT * 128>(wm, buf0, tid);          // L1 chunk0 (overlaps phase 0)

  // phase 0: x = concat(state, action) as plain f16; cols 40..63 zero
  for (int i = tid; i < ROWS_WG * 64; i += 512) {
    int r = i >> 6, c = i & 63;
    int grow = rowbase + r;
    float v = 0.f;
    if (c < SD) v = state[(size_t)grow * SD + c];
    else if (c < SD + AD) v = action[(size_t)grow * AD + (c - SD)];
    s_act[r * AST + c] = (_Float16)v;
  }
  __syncthreads();

  if (cg == 0)
    run_all<4, 2>(0, 0, rg, lane, tid, wm, b1 + e * HID, b2 + e * HID,
                  b3 + e * HID, b4 + e * HID, b5 + e * OUTD, maxlv, minlv,
                  s_act, buf0, buf1);
  else
    run_all<3, 1>(4 + 3 * (cg - 1), 2 + (cg - 1), rg, lane, tid, wm,
                  b1 + e * HID, b2 + e * HID, b3 + e * HID, b4 + e * HID,
                  b5 + e * OUTD, maxlv, minlv, s_act, buf0, buf1);
  __syncthreads();

  // outputs: next_states (E,B,32) then rewards (E,B)
  float* meanb = (float*)s_act;
  float* stdb  = meanb + ROWS_WG * 34;
  const float* nz = noise + (size_t)e * BN * SD1;
  for (int i = tid; i < ROWS_WG * SD; i += 512) {
    int r = i >> 5, c = i & 31;
    int grow = rowbase + r;
    float m = meanb[r * 34 + c], sdv = stdb[r * 34 + c];
    float n0 = nz[(size_t)grow * SD1 + c];
    out[((size_t)e * BN + grow) * SD + c] = state[(size_t)grow * SD + c] + m + sdv * n0;
  }
  if (tid < ROWS_WG) {
    int grow = rowbase + tid;
    float m = meanb[tid * 34 + SD], sdv = stdb[tid * 34 + SD];
    out[(size_t)EN * BN * SD + (size_t)e * BN + grow] =
        m + sdv * nz[(size_t)grow * SD1 + SD];
  }
}

extern "C" void kernel_launch(void* const* d_in, const int* in_sizes, int n_in,
                              void* d_out, int out_size, void* d_ws, size_t ws_size,
                              hipStream_t stream)
{
  (void)in_sizes; (void)n_in; (void)out_size; (void)ws_size;
  const float* state  = (const float*)d_in[0];
  const float* action = (const float*)d_in[1];
  const float* noise  = (const float*)d_in[2];
  const float* W1 = (const float*)d_in[3];  const float* b1 = (const float*)d_in[4];
  const float* W2 = (const float*)d_in[5];  const float* b2 = (const float*)d_in[6];
  const float* W3 = (const float*)d_in[7];  const float* b3 = (const float*)d_in[8];
  const float* W4 = (const float*)d_in[9];  const float* b4 = (const float*)d_in[10];
  const float* W5 = (const float*)d_in[11]; const float* b5 = (const float*)d_in[12];
  const float* mx = (const float*)d_in[13]; const float* mn = (const float*)d_in[14];
  uint32_t* wfrag = (uint32_t*)d_ws;        // 7*334*2048 B = 4.79 MB

  int nfb = EN * BLOCKS_PM;                 // 2338 frag-blocks
  prep_weights<<<(nfb + 3) / 4, 256, 0, stream>>>(W1, W2, W3, W4, W5, wfrag);
  fused_mlp<<<EN * (BN / ROWS_WG), 512, 0, stream>>>(
      state, action, noise, b1, b2, b3, b4, b5, mx, mn, wfrag, (float*)d_out);
}